// Round 2
// baseline (1046.224 us; speedup 1.0000x reference)
//
#include <hip/hip_runtime.h>
#include <math.h>

// Problem constants
#define NN    6272     // tokens per batch = 8*28*28
#define NBAT  2
#define CCH   512      // in channels
#define HCH   256      // hidden channels
#define SPLIT 4        // kv-split factor
#define NTS   49       // kv tiles (of 32) per split chunk: 4*49*32 = 6272

typedef float          f32x4 __attribute__((ext_vector_type(4)));
typedef unsigned int   u32x4 __attribute__((ext_vector_type(4)));
typedef _Float16       f16x8 __attribute__((ext_vector_type(8)));
typedef unsigned short u16x8 __attribute__((ext_vector_type(8)));
typedef unsigned short u16x4 __attribute__((ext_vector_type(4)));

// Scratch as device globals. ~95 MB total.
__device__ __attribute__((aligned(16))) unsigned short g_Xt[NBAT * NN * CCH]; // x transposed [n][m][c] fp16
__device__ __attribute__((aligned(16))) unsigned short g_Wq[HCH * CCH];       // w_theta fp16 [o][c]
__device__ __attribute__((aligned(16))) unsigned short g_Wk[HCH * CCH];       // w_phi
__device__ __attribute__((aligned(16))) unsigned short g_Wv[HCH * CCH];       // w_g
__device__ __attribute__((aligned(16))) unsigned short g_Wo[CCH * HCH];       // w_out [c][o]
__device__ __attribute__((aligned(16))) unsigned short g_Qg[NBAT * NN * HCH]; // theta [n][m][o]
__device__ __attribute__((aligned(16))) unsigned short g_Kg[NBAT * NN * HCH]; // phi   [n][kv][o]
__device__ __attribute__((aligned(16))) unsigned short g_Vt[NBAT * HCH * NN]; // g^T   [n][o][kv]
__device__ __attribute__((aligned(16))) unsigned short g_Yb[NBAT * NN * HCH]; // y     [n][m][o]
__device__ __attribute__((aligned(16))) float g_Yp[SPLIT * NBAT * NN * HCH];  // partial Y (unnormalized, f32)
__device__ __attribute__((aligned(16))) float g_Mp[SPLIT * NBAT * NN];        // partial running max
__device__ __attribute__((aligned(16))) float g_Lp[SPLIT * NBAT * NN];        // partial running sum

static __device__ __forceinline__ unsigned short f2h(float f) {
  _Float16 h = (_Float16)f;
  return __builtin_bit_cast(unsigned short, h);
}
static __device__ __forceinline__ f16x8 ldf(const unsigned short* p) {
  return __builtin_bit_cast(f16x8, *(const u32x4*)p);
}

// ---------------------------------------------------------------- weights
__global__ __launch_bounds__(256) void convw_kernel(const float* __restrict__ wt,
                                                    const float* __restrict__ wp,
                                                    const float* __restrict__ wg,
                                                    const float* __restrict__ wo) {
  int idx = blockIdx.x * 256 + threadIdx.x;   // 0 .. 524287
  int seg = idx >> 17;
  int off = idx & 131071;
  const float* s = (seg == 0) ? wt : (seg == 1) ? wp : (seg == 2) ? wg : wo;
  unsigned short* d = (seg == 0) ? g_Wq : (seg == 1) ? g_Wk : (seg == 2) ? g_Wv : g_Wo;
  d[off] = f2h(s[off]);
}

// ------------------------------------------------- x [n][c][m] -> Xt [n][m][c] fp16
__global__ __launch_bounds__(256) void transpose_kernel(const float* __restrict__ x) {
  __shared__ __attribute__((aligned(16))) float tile[64][72];
  const int tid = threadIdx.x;
  const int m0 = blockIdx.x * 64;
  const int c0 = blockIdx.y * 64;
  const int nb = blockIdx.z;
  const float* src = x + ((size_t)(nb * CCH + c0)) * NN + m0;
#pragma unroll
  for (int p = 0; p < 4; ++p) {
    int r  = p * 16 + (tid >> 4);
    int cc = (tid & 15) * 4;
    *(float4*)&tile[r][cc] = *(const float4*)(src + (size_t)r * NN + cc);
  }
  __syncthreads();
  unsigned short* dstbase = g_Xt + ((size_t)nb * NN + m0) * CCH + c0;
#pragma unroll
  for (int p = 0; p < 2; ++p) {
    int m  = p * 32 + (tid >> 3);
    int cg = (tid & 7) * 8;
    u16x8 v;
#pragma unroll
    for (int j = 0; j < 8; ++j) v[j] = f2h(tile[cg + j][m]);
    *(u16x8*)(dstbase + (size_t)m * CCH + cg) = v;
  }
}

// -------------------------------- theta/phi: out[m][o] = sum_c Xt[m][c] * W[o][c]
__global__ __launch_bounds__(256) void proj_qk_kernel() {
  const int tid  = threadIdx.x;
  const int lane = tid & 63;
  const int w    = tid >> 6;
  const int lo   = lane & 15, hi = lane >> 4;
  const int m0   = blockIdx.x * 64;
  const int nb   = blockIdx.y;
  const int which = blockIdx.z;
  const unsigned short* W  = which ? g_Wk : g_Wq;
  unsigned short*       dst = which ? g_Kg : g_Qg;

  const unsigned short* xrow = g_Xt + ((size_t)nb * NN + m0 + w * 16 + lo) * CCH + hi * 8;
  f32x4 acc[16];
#pragma unroll
  for (int i = 0; i < 16; ++i) acc[i] = (f32x4){0.f, 0.f, 0.f, 0.f};
  for (int ks = 0; ks < 16; ++ks) {
    f16x8 a = ldf(xrow + ks * 32);
#pragma unroll
    for (int of = 0; of < 16; ++of) {
      f16x8 b = ldf(W + (size_t)(of * 16 + lo) * CCH + ks * 32 + hi * 8);
      acc[of] = __builtin_amdgcn_mfma_f32_16x16x32_f16(a, b, acc[of], 0, 0, 0);
    }
  }
  unsigned short* drow = dst + ((size_t)nb * NN + m0 + w * 16 + hi * 4) * HCH + lo;
#pragma unroll
  for (int of = 0; of < 16; ++of)
#pragma unroll
    for (int r = 0; r < 4; ++r)
      drow[(size_t)r * HCH + of * 16] = f2h(acc[of][r]);
}

// -------------------------------- g^T: Vt[o][m] = sum_c Wv[o][c] * Xt[m][c]
__global__ __launch_bounds__(256) void vproj_kernel() {
  const int tid  = threadIdx.x;
  const int lane = tid & 63;
  const int w    = tid >> 6;
  const int lo   = lane & 15, hi = lane >> 4;
  const int m0   = blockIdx.x * 64;
  const int o0   = blockIdx.y * 64;
  const int nb   = blockIdx.z;
  const unsigned short* wrow = g_Wv + (size_t)(o0 + w * 16 + lo) * CCH + hi * 8;
  f32x4 acc[4];
#pragma unroll
  for (int i = 0; i < 4; ++i) acc[i] = (f32x4){0.f, 0.f, 0.f, 0.f};
  for (int ks = 0; ks < 16; ++ks) {
    f16x8 a = ldf(wrow + ks * 32);
#pragma unroll
    for (int mf = 0; mf < 4; ++mf) {
      f16x8 b = ldf(g_Xt + ((size_t)nb * NN + m0 + mf * 16 + lo) * CCH + ks * 32 + hi * 8);
      acc[mf] = __builtin_amdgcn_mfma_f32_16x16x32_f16(a, b, acc[mf], 0, 0, 0);
    }
  }
#pragma unroll
  for (int mf = 0; mf < 4; ++mf)
#pragma unroll
    for (int r = 0; r < 4; ++r)
      g_Vt[((size_t)nb * HCH + o0 + w * 16 + hi * 4 + r) * NN + m0 + mf * 16 + lo] = f2h(acc[mf][r]);
}

// -------------------------------- barrier-free flash attention, kv-split
// Grid: 784 blocks. bid&7 -> (split, batch) combo (XCD-affine); bid>>3 -> m-tile of 64.
// 4 waves, each owns 16 m-rows. K/V B-fragments read directly from global (L1/L2-resident).
// Only LDS use: per-wave P re-layout patch (D-frag -> A-frag). No __syncthreads anywhere.
__global__ __launch_bounds__(256, 3) void attn_kernel() {
  __shared__ __attribute__((aligned(16))) unsigned short Plds[64][40];

  const int tid  = threadIdx.x;
  const int lane = tid & 63;
  const int w    = tid >> 6;           // wave 0..3
  const int lo   = lane & 15, hi = lane >> 4;
  const int bid  = blockIdx.x;
  const int c    = bid & 7;
  const int sp   = c & 3;              // kv split chunk
  const int nb   = c >> 2;             // batch
  const int m0   = (bid >> 3) * 64;
  const int kv0  = sp * (NTS * 32);

  const unsigned short* Kb = g_Kg + (size_t)nb * NN * HCH;
  const unsigned short* Vb = g_Vt + (size_t)nb * HCH * NN;

  // Q fragments in registers: A[m][o], row = m0 + w*16 + lo
  u32x4 qf[8];
  {
    const unsigned short* qrow = g_Qg + ((size_t)nb * NN + m0 + w * 16 + lo) * HCH + hi * 8;
#pragma unroll
    for (int ks = 0; ks < 8; ++ks) qf[ks] = *(const u32x4*)(qrow + ks * 32);
  }

  f32x4 yacc[16];
#pragma unroll
  for (int i = 0; i < 16; ++i) yacc[i] = (f32x4){0.f, 0.f, 0.f, 0.f};
  float mrow[4] = {-3.0e38f, -3.0e38f, -3.0e38f, -3.0e38f};
  float lrow[4] = {0.f, 0.f, 0.f, 0.f};

  for (int t = 0; t < NTS; ++t) {
    const int kvt = kv0 + t * 32;
    // (A) S = Q K^T : B-frags straight from global (L1-shared across the 4 waves)
    f32x4 s0 = (f32x4){0.f, 0.f, 0.f, 0.f};
    f32x4 s1 = (f32x4){0.f, 0.f, 0.f, 0.f};
    const unsigned short* kf = Kb + (size_t)(kvt + lo) * HCH + hi * 8;
#pragma unroll
    for (int ks = 0; ks < 8; ++ks) {
      f16x8 b0 = ldf(kf + ks * 32);
      f16x8 b1 = ldf(kf + 16 * HCH + ks * 32);
      f16x8 a  = __builtin_bit_cast(f16x8, qf[ks]);
      s0 = __builtin_amdgcn_mfma_f32_16x16x32_f16(a, b0, s0, 0, 0, 0);
      s1 = __builtin_amdgcn_mfma_f32_16x16x32_f16(a, b1, s1, 0, 0, 0);
    }
    // (B) online softmax (D-frag rows hi*4+r; reduce 16 lanes = 32 kv cols in 2 frags)
    float fac[4];
#pragma unroll
    for (int r = 0; r < 4; ++r) {
      float sv0 = s0[r] * 16.0f, sv1 = s1[r] * 16.0f;  // pw *= sqrt(256)
      float mx = fmaxf(sv0, sv1);
#pragma unroll
      for (int off = 8; off >= 1; off >>= 1) mx = fmaxf(mx, __shfl_xor(mx, off));
      float mnew = fmaxf(mrow[r], mx);
      fac[r] = __expf(mrow[r] - mnew);
      float p0 = __expf(sv0 - mnew);
      float p1 = __expf(sv1 - mnew);
      float rs = p0 + p1;
#pragma unroll
      for (int off = 8; off >= 1; off >>= 1) rs += __shfl_xor(rs, off);
      lrow[r] = lrow[r] * fac[r] + rs;
      mrow[r] = mnew;
      int prow = w * 16 + hi * 4 + r;
      Plds[prow][lo]      = f2h(p0);
      Plds[prow][16 + lo] = f2h(p1);
    }
#pragma unroll
    for (int of = 0; of < 16; ++of)
#pragma unroll
      for (int r = 0; r < 4; ++r) yacc[of][r] *= fac[r];
    // (C) Y += P V : A = P from per-wave LDS patch, B = Vt rows from global
    {
      f16x8 pa = ldf(&Plds[w * 16 + lo][hi * 8]);
      const unsigned short* vf = Vb + (size_t)lo * NN + kvt + hi * 8;
#pragma unroll
      for (int of = 0; of < 16; ++of) {
        f16x8 b = ldf(vf + (size_t)(of * 16) * NN);
        yacc[of] = __builtin_amdgcn_mfma_f32_16x16x32_f16(pa, b, yacc[of], 0, 0, 0);
      }
    }
  }
  // epilogue: unnormalized partial Y (f32) + running m, l
  {
    float* Yp = g_Yp + (((size_t)sp * NBAT + nb) * NN + m0 + w * 16 + hi * 4) * HCH + lo;
#pragma unroll
    for (int r = 0; r < 4; ++r)
#pragma unroll
      for (int of = 0; of < 16; ++of)
        Yp[(size_t)r * HCH + of * 16] = yacc[of][r];
    if (lo == 0) {
      size_t base = ((size_t)sp * NBAT + nb) * NN + m0 + w * 16 + hi * 4;
#pragma unroll
      for (int r = 0; r < 4; ++r) {
        g_Mp[base + r] = mrow[r];
        g_Lp[base + r] = lrow[r];
      }
    }
  }
}

// -------------------------------- combine kv-split partials -> g_Yb fp16
__global__ __launch_bounds__(256) void combine_kernel() {
  int gid = blockIdx.x * 256 + threadIdx.x;   // 0 .. 802815
  int og  = (gid & 63) * 4;
  int row = gid >> 6;                          // 0 .. 12543 (nb*NN + m)
  int nb  = (row >= NN) ? 1 : 0;
  int m   = row - nb * NN;

  float ms[SPLIT], ls[SPLIT];
#pragma unroll
  for (int s = 0; s < SPLIT; ++s) {
    size_t idx = ((size_t)s * NBAT + nb) * NN + m;
    ms[s] = g_Mp[idx];
    ls[s] = g_Lp[idx];
  }
  float M = ms[0];
#pragma unroll
  for (int s = 1; s < SPLIT; ++s) M = fmaxf(M, ms[s]);
  float wsc[SPLIT];
  float L = 0.f;
#pragma unroll
  for (int s = 0; s < SPLIT; ++s) { wsc[s] = __expf(ms[s] - M); L += wsc[s] * ls[s]; }
  f32x4 acc = (f32x4){0.f, 0.f, 0.f, 0.f};
#pragma unroll
  for (int s = 0; s < SPLIT; ++s) {
    f32x4 y = *(const f32x4*)&g_Yp[(((size_t)s * NBAT + nb) * NN + m) * HCH + og];
    acc += wsc[s] * y;
  }
  float inv = 1.0f / L;
  u16x4 outv;
#pragma unroll
  for (int j = 0; j < 4; ++j) outv[j] = f2h(acc[j] * inv);
  *(u16x4*)&g_Yb[((size_t)nb * NN + m) * HCH + og] = outv;
}

// -------------------------------- out[c][m] = x[c][m] + sum_o Wo[c][o] * y[m][o]
__global__ __launch_bounds__(256) void out_kernel(const float* __restrict__ x,
                                                  float* __restrict__ out) {
  const int tid  = threadIdx.x;
  const int lane = tid & 63;
  const int w    = tid >> 6;
  const int lo   = lane & 15, hi = lane >> 4;
  const int m0   = blockIdx.x * 64;
  const int c0   = blockIdx.y * 64;
  const int nb   = blockIdx.z;
  const unsigned short* wrow = g_Wo + (size_t)(c0 + w * 16 + lo) * HCH + hi * 8;
  f32x4 acc[4];
#pragma unroll
  for (int i = 0; i < 4; ++i) acc[i] = (f32x4){0.f, 0.f, 0.f, 0.f};
#pragma unroll
  for (int ks = 0; ks < 8; ++ks) {
    f16x8 a = ldf(wrow + ks * 32);
#pragma unroll
    for (int mf = 0; mf < 4; ++mf) {
      f16x8 b = ldf(g_Yb + ((size_t)nb * NN + m0 + mf * 16 + lo) * HCH + ks * 32 + hi * 8);
      acc[mf] = __builtin_amdgcn_mfma_f32_16x16x32_f16(a, b, acc[mf], 0, 0, 0);
    }
  }
#pragma unroll
  for (int mf = 0; mf < 4; ++mf)
#pragma unroll
    for (int r = 0; r < 4; ++r) {
      size_t idx = ((size_t)nb * CCH + c0 + w * 16 + hi * 4 + r) * NN + m0 + mf * 16 + lo;
      out[idx] = x[idx] + acc[mf][r];
    }
}

extern "C" void kernel_launch(void* const* d_in, const int* in_sizes, int n_in,
                              void* d_out, int out_size, void* d_ws, size_t ws_size,
                              hipStream_t stream) {
  const float* x  = (const float*)d_in[0];
  const float* wg = (const float*)d_in[1];  // V weight
  const float* wt = (const float*)d_in[2];  // Q weight (theta)
  const float* wp = (const float*)d_in[3];  // K weight (phi)
  const float* wo = (const float*)d_in[4];  // out weight
  float* out = (float*)d_out;
  (void)in_sizes; (void)n_in; (void)d_ws; (void)ws_size; (void)out_size;

  convw_kernel<<<2048, 256, 0, stream>>>(wt, wp, wg, wo);
  transpose_kernel<<<dim3(98, 8, NBAT), 256, 0, stream>>>(x);
  proj_qk_kernel<<<dim3(98, NBAT, 2), 256, 0, stream>>>();
  vproj_kernel<<<dim3(98, 4, NBAT), 256, 0, stream>>>();
  attn_kernel<<<784, 256, 0, stream>>>();
  combine_kernel<<<3136, 256, 0, stream>>>();
  out_kernel<<<dim3(98, 8, NBAT), 256, 0, stream>>>(x, out);
}

// Round 3
// 413.424 us; speedup vs baseline: 2.5306x; 2.5306x over previous
//
#include <hip/hip_runtime.h>
#include <math.h>

// Problem constants
#define NN    6272     // tokens per batch = 8*28*28
#define NBAT  2
#define CCH   512      // in channels
#define HCH   256      // hidden channels
#define SPLIT 4        // kv-split factor
#define NTS   49       // kv tiles (of 32) per split chunk: 4*49*32 = 6272

typedef float          f32x4 __attribute__((ext_vector_type(4)));
typedef unsigned int   u32x4 __attribute__((ext_vector_type(4)));
typedef _Float16       f16x8 __attribute__((ext_vector_type(8)));
typedef unsigned short u16x8 __attribute__((ext_vector_type(8)));
typedef unsigned short u16x4 __attribute__((ext_vector_type(4)));

// Scratch as device globals. ~95 MB total.
__device__ __attribute__((aligned(16))) unsigned short g_Xt[NBAT * NN * CCH]; // x transposed [n][m][c] fp16
__device__ __attribute__((aligned(16))) unsigned short g_Wq[HCH * CCH];       // w_theta fp16 [o][c]
__device__ __attribute__((aligned(16))) unsigned short g_Wk[HCH * CCH];       // w_phi
__device__ __attribute__((aligned(16))) unsigned short g_Wv[HCH * CCH];       // w_g
__device__ __attribute__((aligned(16))) unsigned short g_Wo[CCH * HCH];       // w_out [c][o]
__device__ __attribute__((aligned(16))) unsigned short g_Qg[NBAT * NN * HCH]; // theta [n][m][o]
__device__ __attribute__((aligned(16))) unsigned short g_Kg[NBAT * NN * HCH]; // phi   [n][kv][o]
__device__ __attribute__((aligned(16))) unsigned short g_Vt[NBAT * HCH * NN]; // g^T   [n][o][kv]
__device__ __attribute__((aligned(16))) unsigned short g_Yb[NBAT * NN * HCH]; // y     [n][m][o]
__device__ __attribute__((aligned(16))) float g_Yp[SPLIT * NBAT * NN * HCH];  // partial Y (unnormalized, f32)
__device__ __attribute__((aligned(16))) float g_Mp[SPLIT * NBAT * NN];        // partial running max
__device__ __attribute__((aligned(16))) float g_Lp[SPLIT * NBAT * NN];        // partial running sum

static __device__ __forceinline__ unsigned short f2h(float f) {
  _Float16 h = (_Float16)f;
  return __builtin_bit_cast(unsigned short, h);
}
static __device__ __forceinline__ f16x8 ldf(const unsigned short* p) {
  return __builtin_bit_cast(f16x8, *(const u32x4*)p);
}

// ---------------------------------------------------------------- weights
__global__ __launch_bounds__(256) void convw_kernel(const float* __restrict__ wt,
                                                    const float* __restrict__ wp,
                                                    const float* __restrict__ wg,
                                                    const float* __restrict__ wo) {
  int idx = blockIdx.x * 256 + threadIdx.x;   // 0 .. 524287
  int seg = idx >> 17;
  int off = idx & 131071;
  const float* s = (seg == 0) ? wt : (seg == 1) ? wp : (seg == 2) ? wg : wo;
  unsigned short* d = (seg == 0) ? g_Wq : (seg == 1) ? g_Wk : (seg == 2) ? g_Wv : g_Wo;
  d[off] = f2h(s[off]);
}

// ------------------------------------------------- x [n][c][m] -> Xt [n][m][c] fp16
__global__ __launch_bounds__(256) void transpose_kernel(const float* __restrict__ x) {
  __shared__ __attribute__((aligned(16))) float tile[64][72];
  const int tid = threadIdx.x;
  const int m0 = blockIdx.x * 64;
  const int c0 = blockIdx.y * 64;
  const int nb = blockIdx.z;
  const float* src = x + ((size_t)(nb * CCH + c0)) * NN + m0;
#pragma unroll
  for (int p = 0; p < 4; ++p) {
    int r  = p * 16 + (tid >> 4);
    int cc = (tid & 15) * 4;
    *(float4*)&tile[r][cc] = *(const float4*)(src + (size_t)r * NN + cc);
  }
  __syncthreads();
  unsigned short* dstbase = g_Xt + ((size_t)nb * NN + m0) * CCH + c0;
#pragma unroll
  for (int p = 0; p < 2; ++p) {
    int m  = p * 32 + (tid >> 3);
    int cg = (tid & 7) * 8;
    u16x8 v;
#pragma unroll
    for (int j = 0; j < 8; ++j) v[j] = f2h(tile[cg + j][m]);
    *(u16x8*)(dstbase + (size_t)m * CCH + cg) = v;
  }
}

// -------------------------------- theta/phi: out[m][o] = sum_c Xt[m][c] * W[o][c]
__global__ __launch_bounds__(256) void proj_qk_kernel() {
  const int tid  = threadIdx.x;
  const int lane = tid & 63;
  const int w    = tid >> 6;
  const int lo   = lane & 15, hi = lane >> 4;
  const int m0   = blockIdx.x * 64;
  const int nb   = blockIdx.y;
  const int which = blockIdx.z;
  const unsigned short* W  = which ? g_Wk : g_Wq;
  unsigned short*       dst = which ? g_Kg : g_Qg;

  const unsigned short* xrow = g_Xt + ((size_t)nb * NN + m0 + w * 16 + lo) * CCH + hi * 8;
  f32x4 acc[16];
#pragma unroll
  for (int i = 0; i < 16; ++i) acc[i] = (f32x4){0.f, 0.f, 0.f, 0.f};
  for (int ks = 0; ks < 16; ++ks) {
    f16x8 a = ldf(xrow + ks * 32);
#pragma unroll
    for (int of = 0; of < 16; ++of) {
      f16x8 b = ldf(W + (size_t)(of * 16 + lo) * CCH + ks * 32 + hi * 8);
      acc[of] = __builtin_amdgcn_mfma_f32_16x16x32_f16(a, b, acc[of], 0, 0, 0);
    }
  }
  unsigned short* drow = dst + ((size_t)nb * NN + m0 + w * 16 + hi * 4) * HCH + lo;
#pragma unroll
  for (int of = 0; of < 16; ++of)
#pragma unroll
    for (int r = 0; r < 4; ++r)
      drow[(size_t)r * HCH + of * 16] = f2h(acc[of][r]);
}

// -------------------------------- g^T: Vt[o][m] = sum_c Wv[o][c] * Xt[m][c]
__global__ __launch_bounds__(256) void vproj_kernel() {
  const int tid  = threadIdx.x;
  const int lane = tid & 63;
  const int w    = tid >> 6;
  const int lo   = lane & 15, hi = lane >> 4;
  const int m0   = blockIdx.x * 64;
  const int o0   = blockIdx.y * 64;
  const int nb   = blockIdx.z;
  const unsigned short* wrow = g_Wv + (size_t)(o0 + w * 16 + lo) * CCH + hi * 8;
  f32x4 acc[4];
#pragma unroll
  for (int i = 0; i < 4; ++i) acc[i] = (f32x4){0.f, 0.f, 0.f, 0.f};
  for (int ks = 0; ks < 16; ++ks) {
    f16x8 a = ldf(wrow + ks * 32);
#pragma unroll
    for (int mf = 0; mf < 4; ++mf) {
      f16x8 b = ldf(g_Xt + ((size_t)nb * NN + m0 + mf * 16 + lo) * CCH + ks * 32 + hi * 8);
      acc[mf] = __builtin_amdgcn_mfma_f32_16x16x32_f16(a, b, acc[mf], 0, 0, 0);
    }
  }
#pragma unroll
  for (int mf = 0; mf < 4; ++mf)
#pragma unroll
    for (int r = 0; r < 4; ++r)
      g_Vt[((size_t)nb * HCH + o0 + w * 16 + hi * 4 + r) * NN + m0 + mf * 16 + lo] = f2h(acc[mf][r]);
}

// -------------------------------- LDS-staged flash attention, kv-split
// Grid: 784 blocks. bid&7 -> (split, batch) combo (XCD-affine); bid>>3 -> m-tile of 64.
// 4 waves x 16 m-rows. K/V tiles staged global->reg->LDS (T14 split: issue early,
// commit after the barrier that retires readers). 2 barriers per kv-tile.
__global__ __launch_bounds__(256, 3) void attn_kernel() {
  __shared__ __attribute__((aligned(16))) unsigned short Klds[32][264]; // stride 132w = 4 mod 32 -> 2-way
  __shared__ __attribute__((aligned(16))) unsigned short Vlds[256][40]; // stride 20w -> 2-way
  __shared__ __attribute__((aligned(16))) unsigned short Plds[64][40];

  const int tid  = threadIdx.x;
  const int lane = tid & 63;
  const int w    = tid >> 6;           // wave 0..3
  const int lo   = lane & 15, hi = lane >> 4;
  const int bid  = blockIdx.x;
  const int c    = bid & 7;
  const int sp   = c & 3;              // kv split chunk
  const int nb   = c >> 2;             // batch
  const int m0   = (bid >> 3) * 64;
  const int kv0  = sp * (NTS * 32);

  const unsigned short* Kb = g_Kg + (size_t)nb * NN * HCH;
  const unsigned short* Vb = g_Vt + (size_t)nb * HCH * NN;

  // staging roles (256 threads, 4 passes each of K and V)
  const int krow = tid >> 5;           // 0..7  (+ p*8)
  const int kcol = (tid & 31) * 8;     // 32 x 16B chunks per 256-fp16 row
  const int vrow = tid >> 2;           // 0..63 (+ p*64)
  const int vcol = (tid & 3) * 8;      // 4 x 16B chunks per 32-fp16 row
  u32x4 kreg[4], vreg[4];

  // Q fragments in registers: A[m][o], row = m0 + w*16 + lo
  u32x4 qf[8];
  {
    const unsigned short* qrow = g_Qg + ((size_t)nb * NN + m0 + w * 16 + lo) * HCH + hi * 8;
#pragma unroll
    for (int ks = 0; ks < 8; ++ks) qf[ks] = *(const u32x4*)(qrow + ks * 32);
  }

  f32x4 yacc[16];
#pragma unroll
  for (int i = 0; i < 16; ++i) yacc[i] = (f32x4){0.f, 0.f, 0.f, 0.f};
  float mrow[4] = {-3.0e38f, -3.0e38f, -3.0e38f, -3.0e38f};
  float lrow[4] = {0.f, 0.f, 0.f, 0.f};

  { // prologue: stage tile 0
    const unsigned short* ksrc = Kb + (size_t)(kv0 + krow) * HCH + kcol;
#pragma unroll
    for (int p = 0; p < 4; ++p) kreg[p] = *(const u32x4*)(ksrc + (size_t)p * 8 * HCH);
    const unsigned short* vsrc = Vb + (size_t)vrow * NN + kv0 + vcol;
#pragma unroll
    for (int p = 0; p < 4; ++p) vreg[p] = *(const u32x4*)(vsrc + (size_t)p * 64 * NN);
#pragma unroll
    for (int p = 0; p < 4; ++p) *(u32x4*)&Klds[p * 8 + krow][kcol] = kreg[p];
#pragma unroll
    for (int p = 0; p < 4; ++p) *(u32x4*)&Vlds[p * 64 + vrow][vcol] = vreg[p];
  }
  __syncthreads();

  for (int t = 0; t < NTS; ++t) {
    const int  kvt   = kv0 + t * 32;
    const int  knext = kvt + 32;
    const bool more  = (t + 1 < NTS);
    // (A) issue K loads for next tile (latency hidden under S)
    if (more) {
      const unsigned short* ksrc = Kb + (size_t)(knext + krow) * HCH + kcol;
#pragma unroll
      for (int p = 0; p < 4; ++p) kreg[p] = *(const u32x4*)(ksrc + (size_t)p * 8 * HCH);
    }
    // (B) S = Q K^T  (D[m][kv] = sum_o Q[m][o] * Phi[kv][o])
    f32x4 s0 = (f32x4){0.f, 0.f, 0.f, 0.f};
    f32x4 s1 = (f32x4){0.f, 0.f, 0.f, 0.f};
#pragma unroll
    for (int ks = 0; ks < 8; ++ks) {
      f16x8 b0 = ldf(&Klds[lo][ks * 32 + hi * 8]);
      f16x8 b1 = ldf(&Klds[16 + lo][ks * 32 + hi * 8]);
      f16x8 a  = __builtin_bit_cast(f16x8, qf[ks]);
      s0 = __builtin_amdgcn_mfma_f32_16x16x32_f16(a, b0, s0, 0, 0, 0);
      s1 = __builtin_amdgcn_mfma_f32_16x16x32_f16(a, b1, s1, 0, 0, 0);
    }
    // (C) online softmax (D-frag rows hi*4+r; reduce 16 lanes = 32 kv cols in 2 frags)
    float fac[4];
#pragma unroll
    for (int r = 0; r < 4; ++r) {
      float sv0 = s0[r] * 16.0f, sv1 = s1[r] * 16.0f;  // pw *= sqrt(256)
      float mx = fmaxf(sv0, sv1);
#pragma unroll
      for (int off = 8; off >= 1; off >>= 1) mx = fmaxf(mx, __shfl_xor(mx, off));
      float mnew = fmaxf(mrow[r], mx);
      fac[r] = __expf(mrow[r] - mnew);
      float p0 = __expf(sv0 - mnew);
      float p1 = __expf(sv1 - mnew);
      float rs = p0 + p1;
#pragma unroll
      for (int off = 8; off >= 1; off >>= 1) rs += __shfl_xor(rs, off);
      lrow[r] = lrow[r] * fac[r] + rs;
      mrow[r] = mnew;
      int prow = w * 16 + hi * 4 + r;
      Plds[prow][lo]      = f2h(p0);
      Plds[prow][16 + lo] = f2h(p1);
    }
#pragma unroll
    for (int of = 0; of < 16; ++of)
#pragma unroll
      for (int r = 0; r < 4; ++r) yacc[of][r] *= fac[r];
    __syncthreads();  // bar1: K reads retired; P visible (own-wave anyway)
    // (D) commit next K tile, issue V loads for next tile
    if (more) {
#pragma unroll
      for (int p = 0; p < 4; ++p) *(u32x4*)&Klds[p * 8 + krow][kcol] = kreg[p];
      const unsigned short* vsrc = Vb + (size_t)vrow * NN + knext + vcol;
#pragma unroll
      for (int p = 0; p < 4; ++p) vreg[p] = *(const u32x4*)(vsrc + (size_t)p * 64 * NN);
    }
    // (E) Y += P V  (A = P[m][kv] from own-wave LDS patch, B = Vt[o][kv] tile)
    {
      f16x8 pa = ldf(&Plds[w * 16 + lo][hi * 8]);
#pragma unroll
      for (int of = 0; of < 16; ++of) {
        f16x8 b = ldf(&Vlds[of * 16 + lo][hi * 8]);
        yacc[of] = __builtin_amdgcn_mfma_f32_16x16x32_f16(pa, b, yacc[of], 0, 0, 0);
      }
    }
    __syncthreads();  // bar2: V & P reads retired; K commit visible for next S
    // (F) commit next V tile
    if (more) {
#pragma unroll
      for (int p = 0; p < 4; ++p) *(u32x4*)&Vlds[p * 64 + vrow][vcol] = vreg[p];
    }
  }
  // epilogue: unnormalized partial Y (f32) + running m, l
  {
    float* Yp = g_Yp + (((size_t)sp * NBAT + nb) * NN + m0 + w * 16 + hi * 4) * HCH + lo;
#pragma unroll
    for (int r = 0; r < 4; ++r)
#pragma unroll
      for (int of = 0; of < 16; ++of)
        Yp[(size_t)r * HCH + of * 16] = yacc[of][r];
    if (lo == 0) {
      size_t base = ((size_t)sp * NBAT + nb) * NN + m0 + w * 16 + hi * 4;
#pragma unroll
      for (int r = 0; r < 4; ++r) {
        g_Mp[base + r] = mrow[r];
        g_Lp[base + r] = lrow[r];
      }
    }
  }
}

// -------------------------------- combine kv-split partials -> g_Yb fp16
__global__ __launch_bounds__(256) void combine_kernel() {
  int gid = blockIdx.x * 256 + threadIdx.x;   // 0 .. 802815
  int og  = (gid & 63) * 4;
  int row = gid >> 6;                          // 0 .. 12543 (nb*NN + m)
  int nb  = (row >= NN) ? 1 : 0;
  int m   = row - nb * NN;

  float ms[SPLIT], ls[SPLIT];
#pragma unroll
  for (int s = 0; s < SPLIT; ++s) {
    size_t idx = ((size_t)s * NBAT + nb) * NN + m;
    ms[s] = g_Mp[idx];
    ls[s] = g_Lp[idx];
  }
  float M = ms[0];
#pragma unroll
  for (int s = 1; s < SPLIT; ++s) M = fmaxf(M, ms[s]);
  float wsc[SPLIT];
  float L = 0.f;
#pragma unroll
  for (int s = 0; s < SPLIT; ++s) { wsc[s] = __expf(ms[s] - M); L += wsc[s] * ls[s]; }
  f32x4 acc = (f32x4){0.f, 0.f, 0.f, 0.f};
#pragma unroll
  for (int s = 0; s < SPLIT; ++s) {
    f32x4 y = *(const f32x4*)&g_Yp[(((size_t)s * NBAT + nb) * NN + m) * HCH + og];
    acc += wsc[s] * y;
  }
  float inv = 1.0f / L;
  u16x4 outv;
#pragma unroll
  for (int j = 0; j < 4; ++j) outv[j] = f2h(acc[j] * inv);
  *(u16x4*)&g_Yb[((size_t)nb * NN + m) * HCH + og] = outv;
}

// -------------------------------- out[c][m] = x[c][m] + sum_o Wo[c][o] * y[m][o]
__global__ __launch_bounds__(256) void out_kernel(const float* __restrict__ x,
                                                  float* __restrict__ out) {
  const int tid  = threadIdx.x;
  const int lane = tid & 63;
  const int w    = tid >> 6;
  const int lo   = lane & 15, hi = lane >> 4;
  const int m0   = blockIdx.x * 64;
  const int c0   = blockIdx.y * 64;
  const int nb   = blockIdx.z;
  const unsigned short* wrow = g_Wo + (size_t)(c0 + w * 16 + lo) * HCH + hi * 8;
  f32x4 acc[4];
#pragma unroll
  for (int i = 0; i < 4; ++i) acc[i] = (f32x4){0.f, 0.f, 0.f, 0.f};
#pragma unroll
  for (int ks = 0; ks < 8; ++ks) {
    f16x8 a = ldf(wrow + ks * 32);
#pragma unroll
    for (int mf = 0; mf < 4; ++mf) {
      f16x8 b = ldf(g_Yb + ((size_t)nb * NN + m0 + mf * 16 + lo) * HCH + ks * 32 + hi * 8);
      acc[mf] = __builtin_amdgcn_mfma_f32_16x16x32_f16(a, b, acc[mf], 0, 0, 0);
    }
  }
#pragma unroll
  for (int mf = 0; mf < 4; ++mf)
#pragma unroll
    for (int r = 0; r < 4; ++r) {
      size_t idx = ((size_t)nb * CCH + c0 + w * 16 + hi * 4 + r) * NN + m0 + mf * 16 + lo;
      out[idx] = x[idx] + acc[mf][r];
    }
}

extern "C" void kernel_launch(void* const* d_in, const int* in_sizes, int n_in,
                              void* d_out, int out_size, void* d_ws, size_t ws_size,
                              hipStream_t stream) {
  const float* x  = (const float*)d_in[0];
  const float* wg = (const float*)d_in[1];  // V weight
  const float* wt = (const float*)d_in[2];  // Q weight (theta)
  const float* wp = (const float*)d_in[3];  // K weight (phi)
  const float* wo = (const float*)d_in[4];  // out weight
  float* out = (float*)d_out;
  (void)in_sizes; (void)n_in; (void)d_ws; (void)ws_size; (void)out_size;

  convw_kernel<<<2048, 256, 0, stream>>>(wt, wp, wg, wo);
  transpose_kernel<<<dim3(98, 8, NBAT), 256, 0, stream>>>(x);
  proj_qk_kernel<<<dim3(98, NBAT, 2), 256, 0, stream>>>();
  vproj_kernel<<<dim3(98, 4, NBAT), 256, 0, stream>>>();
  attn_kernel<<<784, 256, 0, stream>>>();
  combine_kernel<<<3136, 256, 0, stream>>>();
  out_kernel<<<dim3(98, 8, NBAT), 256, 0, stream>>>(x, out);
}